// Round 5
// baseline (923.710 us; speedup 1.0000x reference)
//
#include <hip/hip_runtime.h>
#include <cstdint>
#include <cstddef>

#define TSTEPS 1024
#define NB 256
#define NI 128
#define NH 128
#define NC 18
#define CH 32
#define NCHUNK (TSTEPS/CH)   // 32
#define XGS 516              // xgp row stride in f32

#define LOG2E_F     1.44269504088896f
#define TWO_LOG2E_F 2.88539008177793f

typedef _Float16 f16x8 __attribute__((ext_vector_type(8)));
typedef float    f32x4 __attribute__((ext_vector_type(4)));
typedef _Float16 half2_t __attribute__((ext_vector_type(2)));

__device__ __forceinline__ half2_t as_h2(uint32_t v){
  union { uint32_t u; half2_t h; } cv; cv.u = v; return cv.h;
}
__device__ __forceinline__ uint32_t pku(float a, float b){
  union { half2_t h; uint32_t u; } cv; cv.h.x=(_Float16)a; cv.h.y=(_Float16)b; return cv.u;
}
__device__ __forceinline__ float dot2f(half2_t a, half2_t b, float c){
#if __has_builtin(__builtin_amdgcn_fdot2)
  return __builtin_amdgcn_fdot2(a, b, c, false);
#else
  return c + (float)a.x*(float)b.x + (float)a.y*(float)b.y;
#endif
}
__device__ __forceinline__ float fast_rcp(float x){
#if __has_builtin(__builtin_amdgcn_rcpf)
  return __builtin_amdgcn_rcpf(x);
#else
  return 1.f / x;
#endif
}
__device__ __forceinline__ float exp2x(float v){
#if __has_builtin(__builtin_amdgcn_exp2f)
  return __builtin_amdgcn_exp2f(v);
#else
  return __expf(v * 0.6931471805599453f);
#endif
}
// quad-broadcast via DPP: CTRL = k*0x55 broadcasts lane k of each 4-lane group
template<int CTRL>
__device__ __forceinline__ float qbcast(float v){
#if __has_builtin(__builtin_amdgcn_mov_dpp)
  union { float f; int i; } u; u.f = v;
  u.i = __builtin_amdgcn_mov_dpp(u.i, CTRL, 0xF, 0xF, false);
  return u.f;
#else
  return __shfl(v, ((threadIdx.x & 63) & ~3) + (CTRL & 3), 64);
#endif
}
// 8 consecutive f32 -> f16x8 with scale (one MFMA operand row-slice)
__device__ __forceinline__ f16x8 ldrow_f16s(const float* base, float s){
  float4 f0 = ((const float4*)base)[0];
  float4 f1 = ((const float4*)base)[1];
  f16x8 r;
  r[0]=(_Float16)(f0.x*s); r[1]=(_Float16)(f0.y*s); r[2]=(_Float16)(f0.z*s); r[3]=(_Float16)(f0.w*s);
  r[4]=(_Float16)(f1.x*s); r[5]=(_Float16)(f1.y*s); r[6]=(_Float16)(f1.z*s); r[7]=(_Float16)(f1.w*s);
  return r;
}
// lgkm-only workgroup barrier: all in-loop cross-wave deps are LDS; global
// prefetch loads and out-stores stay in flight across it.
__device__ __forceinline__ void barrier_lds(){
  asm volatile("s_waitcnt lgkmcnt(0)" ::: "memory");
  __builtin_amdgcn_s_barrier();
}

// One block per batch row, 256 threads = 4 waves, ONE wave per SIMD.
// Wave w owns cells w*32..w*32+31 via 8 MFMA col-groups m (32 MFMA/step/wave):
// col n of group m <-> W-row (n&3)*128 + w*32 + (m&3)*8 + (n>>2)*2 + (m>>2).
// Lane (quad,c4,q4) owns cellA = w*32+quad*8+c4*2 (m=quad) and cellB=cellA+1
// (m=quad+4) -> packed single ds_write_b32 per step.
// Whh AND Wih register-resident (256 VGPRs; 1 wave/SIMD allows up to 512).
// Unified activation (r4): weights/bias pre-scaled by log2e (2*log2e for g).
__global__ __launch_bounds__(256, 1) void lstm_mfma(
    const float* __restrict__ x,      // [T,B,I]
    const float* __restrict__ h0,     // [B,H]
    const float* __restrict__ c0,     // [B,H]
    const float* __restrict__ Wih,    // [4H,I]
    const float* __restrict__ Whh,    // [4H,H]
    const float* __restrict__ bih,    // [4H]
    const float* __restrict__ bhh,    // [4H]
    const float* __restrict__ fcW,    // [18,H]
    const float* __restrict__ fcb,    // [18]
    float* __restrict__ out,          // [T,B,18]
    float* __restrict__ hT,           // [B,H]
    float* __restrict__ cT)           // [B,H]
{
  const int b    = blockIdx.x;
  const int tid  = threadIdx.x;
  const int w    = tid >> 6;      // wave 0..3
  const int l    = tid & 63;
  const int n    = l & 15;        // tile col
  const int quad = l >> 4;        // k-chunk within frag / group-select
  const int q4   = l & 3;         // gate type of this lane
  const int c4   = (l >> 2) & 3;

  __shared__ __align__(16) _Float16 xs[CH][136];    // x chunk f16 (+pad)      8704 B
  __shared__ __align__(16) float    xgp[CH][XGS];   // x-gates f32            66048 B
  __shared__ __align__(16) _Float16 hist[CH][128];  // h ring / history        8192 B
  __shared__ __align__(16) uint32_t fcw[NC][66];    // head W f16 (+pad)       4752 B

  // ---- persistent weight B-frags: Whh + Wih, [m][kt], 256 VGPRs ----
  const float sc = (q4 == 2) ? TWO_LOG2E_F : LOG2E_F;
  f16x8 whh[8][4], wih[8][4];
  float biasv[8];
#pragma unroll
  for (int m = 0; m < 8; ++m){
    const int row = q4*128 + w*32 + (m&3)*8 + (n>>2)*2 + (m>>2);
#pragma unroll
    for (int kt = 0; kt < 4; ++kt){
      whh[m][kt] = ldrow_f16s(Whh + (size_t)row*NH + kt*32 + quad*8, sc);
      wih[m][kt] = ldrow_f16s(Wih + (size_t)row*NI + kt*32 + quad*8, sc);
    }
    biasv[m] = (bih[row] + bhh[row]) * sc;
  }

  // ---- unified-activation per-lane constants ----
  const uint32_t smask = (q4 == 2) ? 0u : 0x80000000u;
  const float aK = (q4 == 2) ? 1.f : 0.f;
  const float sK = (q4 == 2) ? -2.f : 1.f;

  // ---- per-lane cell state (2 adjacent cells, 4 redundant lanes each) ----
  const int cellA = w*32 + quad*8 + c4*2;    // cellB = cellA+1
  float cstA = c0[(size_t)b*NH + cellA];
  float cstB = c0[(size_t)b*NH + cellA + 1];
  float hlastA = 0.f, hlastB = 0.f;

  if (tid < 128) hist[CH-1][tid] = (_Float16)h0[(size_t)b*NH + tid];  // ring seed
#pragma unroll
  for (int r = 0; r < 5; ++r){
    int idx = tid + 256*r;                   // 18*64 = 1152 targets
    if (idx < NC*64){
      int j = idx >> 6, k = idx & 63;
      float2 f = ((const float2*)(fcW + (size_t)j*NH))[k];
      fcw[j][k] = pku(f.x, f.y);
    }
  }

  // ---- head constants ----
  const int hrow = tid >> 3;                 // 0..31
  const int hj   = tid & 7;
  const float fj0 = fcb[hj];
  const float fj1 = fcb[hj + 8];
  const float fj2 = (hj < 2) ? fcb[16 + hj] : 0.f;

  // ---- prefetch x chunk 0 into registers (4 float4/thread) ----
  const int srow = tid >> 3;                 // 0..31
  const int sc8  = tid & 7;
  float4 xp0 = ((const float4*)(x + ((size_t)srow*NB + b)*NI))[sc8];
  float4 xp1 = ((const float4*)(x + ((size_t)srow*NB + b)*NI))[sc8 + 8];
  float4 xp2 = ((const float4*)(x + ((size_t)srow*NB + b)*NI))[sc8 + 16];
  float4 xp3 = ((const float4*)(x + ((size_t)srow*NB + b)*NI))[sc8 + 24];
  __syncthreads();

#pragma unroll 1
  for (int ck = 0; ck < NCHUNK; ++ck){
    const int t0 = ck*CH;

    // ---------- xs <- prefetched registers (f16) ----------
    {
      union { _Float16 h[4]; uint2 u2; } p0, p1, p2, p3;
      p0.h[0]=(_Float16)xp0.x; p0.h[1]=(_Float16)xp0.y; p0.h[2]=(_Float16)xp0.z; p0.h[3]=(_Float16)xp0.w;
      p1.h[0]=(_Float16)xp1.x; p1.h[1]=(_Float16)xp1.y; p1.h[2]=(_Float16)xp1.z; p1.h[3]=(_Float16)xp1.w;
      p2.h[0]=(_Float16)xp2.x; p2.h[1]=(_Float16)xp2.y; p2.h[2]=(_Float16)xp2.z; p2.h[3]=(_Float16)xp2.w;
      p3.h[0]=(_Float16)xp3.x; p3.h[1]=(_Float16)xp3.y; p3.h[2]=(_Float16)xp3.z; p3.h[3]=(_Float16)xp3.w;
      *(uint2*)&xs[srow][4*sc8]        = p0.u2;
      *(uint2*)&xs[srow][4*(sc8 + 8)]  = p1.u2;
      *(uint2*)&xs[srow][4*(sc8 + 16)] = p2.u2;
      *(uint2*)&xs[srow][4*(sc8 + 24)] = p3.u2;
    }
    barrier_lds();   // xs ready; also orders prev head's hist reads before new hist writes

    // ---------- x-GEMM: XG[32,512] = X @ Wih^T + bias ----------
    {
      f16x8 xa[2][4];                        // A-frags [mt][kt]
#pragma unroll
      for (int mt = 0; mt < 2; ++mt)
#pragma unroll
        for (int kt = 0; kt < 4; ++kt)
          xa[mt][kt] = *(const f16x8*)&xs[mt*16 + n][kt*32 + quad*8];

#pragma unroll
      for (int m = 0; m < 8; ++m){
#pragma unroll
        for (int mt = 0; mt < 2; ++mt){
          f32x4 acc = { biasv[m], biasv[m], biasv[m], biasv[m] };
#pragma unroll
          for (int kt = 0; kt < 4; ++kt)
            acc = __builtin_amdgcn_mfma_f32_16x16x32_f16(xa[mt][kt], wih[m][kt], acc, 0, 0, 0);
#pragma unroll
          for (int r = 0; r < 4; ++r)
            xgp[mt*16 + quad*4 + r][w*128 + n*8 + m] = acc[r];
        }
      }
    }

    // issue next chunk's x loads now; lgkm-only barriers keep them in flight
    if (ck + 1 < NCHUNK){
      const size_t t1 = (size_t)(t0 + CH);
      xp0 = ((const float4*)(x + ((t1 + srow)*NB + b)*NI))[sc8];
      xp1 = ((const float4*)(x + ((t1 + srow)*NB + b)*NI))[sc8 + 8];
      xp2 = ((const float4*)(x + ((t1 + srow)*NB + b)*NI))[sc8 + 16];
      xp3 = ((const float4*)(x + ((t1 + srow)*NB + b)*NI))[sc8 + 24];
    }
    barrier_lds();   // xgp ready

    // ---------- 32 recurrent steps ----------
#pragma unroll 2
    for (int tt = 0; tt < CH; ++tt){
      f32x4 s0 = *(const f32x4*)&xgp[tt][w*128 + n*8];
      f32x4 s1 = *(const f32x4*)&xgp[tt][w*128 + n*8 + 4];
      const int rp = (tt + CH - 1) & (CH - 1);
      const _Float16* hprev = &hist[rp][0];
      f16x8 a0 = *(const f16x8*)&hprev[ 0 + quad*8];
      f16x8 a1 = *(const f16x8*)&hprev[32 + quad*8];
      f16x8 a2 = *(const f16x8*)&hprev[64 + quad*8];
      f16x8 a3 = *(const f16x8*)&hprev[96 + quad*8];
      float g[8];
#pragma unroll
      for (int m = 0; m < 4; ++m){
        f32x4 aA, aB;
        aA[0] = s0[m];
        aA = __builtin_amdgcn_mfma_f32_16x16x32_f16(a0, whh[m][0], aA, 0, 0, 0);
        aA = __builtin_amdgcn_mfma_f32_16x16x32_f16(a1, whh[m][1], aA, 0, 0, 0);
        aB[0] = 0.f;
        aB = __builtin_amdgcn_mfma_f32_16x16x32_f16(a2, whh[m][2], aB, 0, 0, 0);
        aB = __builtin_amdgcn_mfma_f32_16x16x32_f16(a3, whh[m][3], aB, 0, 0, 0);
        g[m] = aA[0] + aB[0];
      }
#pragma unroll
      for (int m = 0; m < 4; ++m){
        f32x4 aA, aB;
        aA[0] = s1[m];
        aA = __builtin_amdgcn_mfma_f32_16x16x32_f16(a0, whh[4+m][0], aA, 0, 0, 0);
        aA = __builtin_amdgcn_mfma_f32_16x16x32_f16(a1, whh[4+m][1], aA, 0, 0, 0);
        aB[0] = 0.f;
        aB = __builtin_amdgcn_mfma_f32_16x16x32_f16(a2, whh[4+m][2], aB, 0, 0, 0);
        aB = __builtin_amdgcn_mfma_f32_16x16x32_f16(a3, whh[4+m][3], aB, 0, 0, 0);
        g[4+m] = aA[0] + aB[0];
      }
      // select this lane's two (cell,gate) values: group = quad and quad+4
      const bool qlo = (quad & 1) != 0;
      const bool qhi = (quad & 2) != 0;
      float gsA = qhi ? (qlo ? g[3] : g[2]) : (qlo ? g[1] : g[0]);
      float gsB = qhi ? (qlo ? g[7] : g[6]) : (qlo ? g[5] : g[4]);
      // unified activation for both cells (sigmoid q!=2, tanh q==2)
      union { float f; uint32_t u; } ga, gb;
      ga.f = gsA; ga.u ^= smask;
      gb.f = gsB; gb.u ^= smask;
      float actA = __builtin_fmaf(sK, fast_rcp(1.f + exp2x(ga.f)), aK);
      float actB = __builtin_fmaf(sK, fast_rcp(1.f + exp2x(gb.f)), aK);
      // gather i,f,g,o from the 4 adjacent lanes (free DPP)
      float viA = qbcast<0x00>(actA), vfA = qbcast<0x55>(actA);
      float vgA = qbcast<0xAA>(actA), voA = qbcast<0xFF>(actA);
      float viB = qbcast<0x00>(actB), vfB = qbcast<0x55>(actB);
      float vgB = qbcast<0xAA>(actB), voB = qbcast<0xFF>(actB);
      cstA = __builtin_fmaf(vfA, cstA, viA*vgA);
      cstB = __builtin_fmaf(vfB, cstB, viB*vgB);
      float tcA = __builtin_fmaf(-2.f, fast_rcp(1.f + exp2x(cstA * TWO_LOG2E_F)), 1.f);
      float tcB = __builtin_fmaf(-2.f, fast_rcp(1.f + exp2x(cstB * TWO_LOG2E_F)), 1.f);
      float hvA = voA * tcA;
      float hvB = voB * tcB;
      hlastA = hvA; hlastB = hvB;
      if (q4 == 0)                           // one writer per cell pair, packed
        *(uint32_t*)&hist[tt][cellA] = pku(hvA, hvB);
      barrier_lds();
    }

    // ---------- fused head for this chunk ----------
    {
      const uint4* hb = (const uint4*)&hist[hrow][0];
#pragma unroll
      for (int jj = 0; jj < 3; ++jj){
        const int j = (jj == 0) ? hj : (jj == 1) ? hj + 8 : 16 + hj;
        const float fb0 = (jj == 0) ? fj0 : (jj == 1) ? fj1 : fj2;
        if (jj < 2 || hj < 2){
          const uint2* fw = (const uint2*)&fcw[j][0];
          float a0=0.f, a1=0.f, a2=0.f, a3=0.f;
#pragma unroll
          for (int k = 0; k < 16; ++k){
            uint4 v = hb[k];
            uint2 fa = fw[2*k], fb2 = fw[2*k+1];
            a0 = dot2f(as_h2(fa.x),  as_h2(v.x), a0);
            a1 = dot2f(as_h2(fa.y),  as_h2(v.y), a1);
            a2 = dot2f(as_h2(fb2.x), as_h2(v.z), a2);
            a3 = dot2f(as_h2(fb2.y), as_h2(v.w), a3);
          }
          out[(size_t)(t0+hrow)*NB*NC + (size_t)b*NC + j] =
              (a0+a1) + (a2+a3) + fb0;
        }
      }
    }
  }

  // ---------- final hT / cT (from registers, packed float2) ----------
  if (q4 == 0){
    *(float2*)&hT[(size_t)b*NH + cellA] = make_float2(hlastA, hlastB);
    *(float2*)&cT[(size_t)b*NH + cellA] = make_float2(cstA, cstB);
  }
}

extern "C" void kernel_launch(void* const* d_in, const int* in_sizes, int n_in,
                              void* d_out, int out_size, void* d_ws, size_t ws_size,
                              hipStream_t stream) {
  (void)in_sizes; (void)n_in; (void)d_ws; (void)ws_size; (void)out_size;
  const float* x   = (const float*)d_in[0];
  const float* h0  = (const float*)d_in[1];
  const float* c0  = (const float*)d_in[2];
  const float* Wih = (const float*)d_in[3];
  const float* Whh = (const float*)d_in[4];
  const float* bih = (const float*)d_in[5];
  const float* bhh = (const float*)d_in[6];
  const float* fcW = (const float*)d_in[7];
  const float* fcb = (const float*)d_in[8];
  float* out = (float*)d_out;
  float* hT  = out + (size_t)TSTEPS*NB*NC;   // 4,718,592
  float* cT  = hT + (size_t)NB*NH;           // +32,768
  hipLaunchKernelGGL(lstm_mfma, dim3(NB), dim3(256), 0, stream,
                     x, h0, c0, Wih, Whh, bih, bhh, fcW, fcb, out, hT, cT);
}

// Round 6
// 869.699 us; speedup vs baseline: 1.0621x; 1.0621x over previous
//
#include <hip/hip_runtime.h>
#include <cstdint>
#include <cstddef>

#define TSTEPS 1024
#define NB 256
#define NI 128
#define NH 128
#define NC 18
#define CH 32
#define NCHUNK (TSTEPS/CH)   // 32
#define XGS 516              // xgp row stride in f32

#define LOG2E_F     1.44269504088896f
#define TWO_LOG2E_F 2.88539008177793f

typedef _Float16 f16x8 __attribute__((ext_vector_type(8)));
typedef float    f32x4 __attribute__((ext_vector_type(4)));
typedef _Float16 half2_t __attribute__((ext_vector_type(2)));

__device__ __forceinline__ half2_t as_h2(uint32_t v){
  union { uint32_t u; half2_t h; } cv; cv.u = v; return cv.h;
}
__device__ __forceinline__ uint32_t pku(float a, float b){
  union { half2_t h; uint32_t u; } cv; cv.h.x=(_Float16)a; cv.h.y=(_Float16)b; return cv.u;
}
__device__ __forceinline__ float dot2f(half2_t a, half2_t b, float c){
#if __has_builtin(__builtin_amdgcn_fdot2)
  return __builtin_amdgcn_fdot2(a, b, c, false);
#else
  return c + (float)a.x*(float)b.x + (float)a.y*(float)b.y;
#endif
}
__device__ __forceinline__ float fast_rcp(float x){
#if __has_builtin(__builtin_amdgcn_rcpf)
  return __builtin_amdgcn_rcpf(x);
#else
  return 1.f / x;
#endif
}
__device__ __forceinline__ float exp2x(float v){
#if __has_builtin(__builtin_amdgcn_exp2f)
  return __builtin_amdgcn_exp2f(v);
#else
  return __expf(v * 0.6931471805599453f);
#endif
}
// quad-broadcast via DPP: CTRL = k*0x55 broadcasts lane k of each 4-lane group
template<int CTRL>
__device__ __forceinline__ float qbcast(float v){
#if __has_builtin(__builtin_amdgcn_mov_dpp)
  union { float f; int i; } u; u.f = v;
  u.i = __builtin_amdgcn_mov_dpp(u.i, CTRL, 0xF, 0xF, false);
  return u.f;
#else
  return __shfl(v, ((threadIdx.x & 63) & ~3) + (CTRL & 3), 64);
#endif
}
// 8 consecutive f32 -> f16x8 with scale (one MFMA operand row-slice)
__device__ __forceinline__ f16x8 ldrow_f16s(const float* base, float s){
  float4 f0 = ((const float4*)base)[0];
  float4 f1 = ((const float4*)base)[1];
  f16x8 r;
  r[0]=(_Float16)(f0.x*s); r[1]=(_Float16)(f0.y*s); r[2]=(_Float16)(f0.z*s); r[3]=(_Float16)(f0.w*s);
  r[4]=(_Float16)(f1.x*s); r[5]=(_Float16)(f1.y*s); r[6]=(_Float16)(f1.z*s); r[7]=(_Float16)(f1.w*s);
  return r;
}
// lgkm-only workgroup barrier: all in-loop cross-wave deps are LDS; global
// prefetch loads and out-stores stay in flight across it.
__device__ __forceinline__ void barrier_lds(){
  asm volatile("s_waitcnt lgkmcnt(0)" ::: "memory");
  __builtin_amdgcn_s_barrier();
}

// One block per batch row, 1024 threads = 16 waves, FOUR waves per SIMD.
// Wave w owns cells [w*8, w*8+8) via 2 MFMA col-groups m (8 MFMA/step/wave;
// per-SIMD MFMA issue unchanged vs the 8-wave version, but 4 waves now
// interleave their serial tails with each other's MFMA streams).
// Col n of group m <-> W-row (n&3)*128 + w*8 + m*4 + (n>>2).
// Lane l = quad*16 + c4*4 + q4 activates cell w*8 + (quad>>1)*4 + c4
// (duplicated across the quad&1 pair; writer = q4==0 && !(quad&1)).
// Unified activation: weights/bias pre-scaled by log2e (2*log2e for g-gate),
// sigmoid/tanh share one exp2+rcp+fma with per-lane constants.
__global__ __launch_bounds__(1024, 1) void lstm_mfma(
    const float* __restrict__ x,      // [T,B,I]
    const float* __restrict__ h0,     // [B,H]
    const float* __restrict__ c0,     // [B,H]
    const float* __restrict__ Wih,    // [4H,I]
    const float* __restrict__ Whh,    // [4H,H]
    const float* __restrict__ bih,    // [4H]
    const float* __restrict__ bhh,    // [4H]
    const float* __restrict__ fcW,    // [18,H]
    const float* __restrict__ fcb,    // [18]
    float* __restrict__ out,          // [T,B,18]
    float* __restrict__ hT,           // [B,H]
    float* __restrict__ cT)           // [B,H]
{
  const int b    = blockIdx.x;
  const int tid  = threadIdx.x;
  const int w    = tid >> 6;      // wave 0..15
  const int l    = tid & 63;
  const int n    = l & 15;        // tile col
  const int quad = l >> 4;        // k-chunk within frag
  const int q4   = l & 3;         // gate type of this lane
  const int c4   = (l >> 2) & 3;
  const int mg   = quad >> 1;     // lane's col-group (0/1)

  __shared__ __align__(16) _Float16 xs[CH][136];    // x chunk f16 (+pad)      8704 B
  __shared__ __align__(16) float    xgp[CH][XGS];   // x-gates f32            66048 B
  __shared__ __align__(16) _Float16 hist[CH][128];  // h ring / history        8192 B
  __shared__ __align__(16) uint32_t fcw[NC][66];    // head W f16 (+pad)       4752 B

  // ---- persistent weight B-frags: Whh + Wih, [m][kt], 64 VGPRs ----
  const float sc = (q4 == 2) ? TWO_LOG2E_F : LOG2E_F;
  f16x8 whh[2][4], wih[2][4];
  float biasv[2];
#pragma unroll
  for (int m = 0; m < 2; ++m){
    const int row = q4*128 + w*8 + m*4 + c4;
#pragma unroll
    for (int kt = 0; kt < 4; ++kt){
      whh[m][kt] = ldrow_f16s(Whh + (size_t)row*NH + kt*32 + quad*8, sc);
      wih[m][kt] = ldrow_f16s(Wih + (size_t)row*NI + kt*32 + quad*8, sc);
    }
    biasv[m] = (bih[row] + bhh[row]) * sc;
  }

  // ---- unified-activation per-lane constants ----
  const uint32_t smask = (q4 == 2) ? 0u : 0x80000000u;
  const float aK = (q4 == 2) ? 1.f : 0.f;
  const float sK = (q4 == 2) ? -2.f : 1.f;

  // ---- per-lane cell state (8 redundant lanes per cell across quad&1 pair) ----
  const int mycell = w*8 + mg*4 + c4;
  float cst = c0[(size_t)b*NH + mycell];
  float hlast = 0.f;
  const bool writer = (q4 == 0) && ((quad & 1) == 0);

  if (tid < 128) hist[CH-1][tid] = (_Float16)h0[(size_t)b*NH + tid];  // ring seed
#pragma unroll
  for (int r = 0; r < 2; ++r){
    int idx = tid + 1024*r;                  // 18*64 = 1152 targets
    if (idx < NC*64){
      int j = idx >> 6, k = idx & 63;
      float2 f = ((const float2*)(fcW + (size_t)j*NH))[k];
      fcw[j][k] = pku(f.x, f.y);
    }
  }

  // ---- head constants ----
  const int hrow = tid >> 5;                 // 0..31
  const int hj   = tid & 31;
  const float fjh = (hj < NC) ? fcb[hj] : 0.f;

  // ---- prefetch x chunk 0 into registers (1 float4/thread) ----
  const int srow = tid >> 5;                 // 0..31
  const int sc32 = tid & 31;
  float4 xp = ((const float4*)(x + ((size_t)srow*NB + b)*NI))[sc32];
  __syncthreads();

#pragma unroll 1
  for (int ck = 0; ck < NCHUNK; ++ck){
    const int t0 = ck*CH;

    // ---------- xs <- prefetched register (f16) ----------
    {
      union { _Float16 h[4]; uint2 u2; } p;
      p.h[0]=(_Float16)xp.x; p.h[1]=(_Float16)xp.y;
      p.h[2]=(_Float16)xp.z; p.h[3]=(_Float16)xp.w;
      *(uint2*)&xs[srow][4*sc32] = p.u2;
    }
    barrier_lds();   // xs ready; also orders prev head's hist reads before new hist writes

    // ---------- x-GEMM: XG[32,512] = X @ Wih^T + bias ----------
    {
      f16x8 xa[2][4];                        // A-frags [mt][kt]
#pragma unroll
      for (int mt = 0; mt < 2; ++mt)
#pragma unroll
        for (int kt = 0; kt < 4; ++kt)
          xa[mt][kt] = *(const f16x8*)&xs[mt*16 + n][kt*32 + quad*8];

#pragma unroll
      for (int m = 0; m < 2; ++m){
#pragma unroll
        for (int mt = 0; mt < 2; ++mt){
          f32x4 acc = { biasv[m], biasv[m], biasv[m], biasv[m] };
#pragma unroll
          for (int kt = 0; kt < 4; ++kt)
            acc = __builtin_amdgcn_mfma_f32_16x16x32_f16(xa[mt][kt], wih[m][kt], acc, 0, 0, 0);
#pragma unroll
          for (int r = 0; r < 4; ++r)
            xgp[mt*16 + quad*4 + r][w*32 + n*2 + m] = acc[r];
        }
      }
    }

    // issue next chunk's x load now; lgkm-only barriers keep it in flight
    if (ck + 1 < NCHUNK){
      const size_t t1 = (size_t)(t0 + CH);
      xp = ((const float4*)(x + ((t1 + srow)*NB + b)*NI))[sc32];
    }
    barrier_lds();   // xgp ready

    // ---------- 32 recurrent steps ----------
#pragma unroll 2
    for (int tt = 0; tt < CH; ++tt){
      // this lane's 2 seeds (groups m=0,1) adjacent: ONE b64
      float2 sg2 = *(const float2*)&xgp[tt][w*32 + n*2];
      const int rp = (tt + CH - 1) & (CH - 1);
      const _Float16* hprev = &hist[rp][0];
      f16x8 a0 = *(const f16x8*)&hprev[ 0 + quad*8];
      f16x8 a1 = *(const f16x8*)&hprev[32 + quad*8];
      f16x8 a2 = *(const f16x8*)&hprev[64 + quad*8];
      f16x8 a3 = *(const f16x8*)&hprev[96 + quad*8];
      float g0, g1;
      {
        f32x4 aA, aB;
        aA[0] = sg2.x;
        aA = __builtin_amdgcn_mfma_f32_16x16x32_f16(a0, whh[0][0], aA, 0, 0, 0);
        aA = __builtin_amdgcn_mfma_f32_16x16x32_f16(a1, whh[0][1], aA, 0, 0, 0);
        aB[0] = 0.f;
        aB = __builtin_amdgcn_mfma_f32_16x16x32_f16(a2, whh[0][2], aB, 0, 0, 0);
        aB = __builtin_amdgcn_mfma_f32_16x16x32_f16(a3, whh[0][3], aB, 0, 0, 0);
        g0 = aA[0] + aB[0];
      }
      {
        f32x4 aA, aB;
        aA[0] = sg2.y;
        aA = __builtin_amdgcn_mfma_f32_16x16x32_f16(a0, whh[1][0], aA, 0, 0, 0);
        aA = __builtin_amdgcn_mfma_f32_16x16x32_f16(a1, whh[1][1], aA, 0, 0, 0);
        aB[0] = 0.f;
        aB = __builtin_amdgcn_mfma_f32_16x16x32_f16(a2, whh[1][2], aB, 0, 0, 0);
        aB = __builtin_amdgcn_mfma_f32_16x16x32_f16(a3, whh[1][3], aB, 0, 0, 0);
        g1 = aA[0] + aB[0];
      }
      // select this lane's (cell,gate) value: group = quad>>1
      float gsel = (quad & 2) ? g1 : g0;
      // unified activation (sigmoid q!=2, tanh q==2), all lanes
      union { float f; uint32_t u; } gx; gx.f = gsel; gx.u ^= smask;
      float act = __builtin_fmaf(sK, fast_rcp(1.f + exp2x(gx.f)), aK);
      // gather i,f,g,o of this cell from the 4 adjacent lanes (free DPP)
      float vi = qbcast<0x00>(act);
      float vf = qbcast<0x55>(act);
      float vg = qbcast<0xAA>(act);
      float vo = qbcast<0xFF>(act);
      cst = __builtin_fmaf(vf, cst, vi*vg);
      float tc = __builtin_fmaf(-2.f, fast_rcp(1.f + exp2x(cst * TWO_LOG2E_F)), 1.f);
      float hv = vo * tc;
      hlast = hv;
      if (writer)                            // one writer per cell
        hist[tt][mycell] = (_Float16)hv;
      barrier_lds();
    }

    // ---------- fused head for this chunk (1 output per active thread) ----------
    if (hj < NC){
      const uint4* hb = (const uint4*)&hist[hrow][0];
      const uint2* fw = (const uint2*)&fcw[hj][0];
      float a0=0.f, a1=0.f, a2=0.f, a3=0.f;
#pragma unroll
      for (int k = 0; k < 16; ++k){
        uint4 v = hb[k];
        uint2 fa = fw[2*k], fb2 = fw[2*k+1];
        a0 = dot2f(as_h2(fa.x),  as_h2(v.x), a0);
        a1 = dot2f(as_h2(fa.y),  as_h2(v.y), a1);
        a2 = dot2f(as_h2(fb2.x), as_h2(v.z), a2);
        a3 = dot2f(as_h2(fb2.y), as_h2(v.w), a3);
      }
      out[(size_t)(t0+hrow)*NB*NC + (size_t)b*NC + hj] =
          (a0+a1) + (a2+a3) + fjh;
    }
  }

  // ---------- final hT / cT (from registers, one writer per cell) ----------
  if (writer){
    hT[(size_t)b*NH + mycell] = hlast;
    cT[(size_t)b*NH + mycell] = cst;
  }
}

extern "C" void kernel_launch(void* const* d_in, const int* in_sizes, int n_in,
                              void* d_out, int out_size, void* d_ws, size_t ws_size,
                              hipStream_t stream) {
  (void)in_sizes; (void)n_in; (void)d_ws; (void)ws_size; (void)out_size;
  const float* x   = (const float*)d_in[0];
  const float* h0  = (const float*)d_in[1];
  const float* c0  = (const float*)d_in[2];
  const float* Wih = (const float*)d_in[3];
  const float* Whh = (const float*)d_in[4];
  const float* bih = (const float*)d_in[5];
  const float* bhh = (const float*)d_in[6];
  const float* fcW = (const float*)d_in[7];
  const float* fcb = (const float*)d_in[8];
  float* out = (float*)d_out;
  float* hT  = out + (size_t)TSTEPS*NB*NC;   // 4,718,592
  float* cT  = hT + (size_t)NB*NH;           // +32,768
  hipLaunchKernelGGL(lstm_mfma, dim3(NB), dim3(1024), 0, stream,
                     x, h0, c0, Wih, Whh, bih, bhh, fcW, fcb, out, hT, cT);
}